// Round 4
// baseline (542.244 us; speedup 1.0000x reference)
//
#include <hip/hip_runtime.h>
#include <hip/hip_bf16.h>
#include <stdint.h>

// Problem constants
#define B_    2
#define S_    2048
#define HID_  2048
#define H_    16
#define KV_   2
#define D_    128
#define ROT_  32
#define NQG   4096   // H*2D
#define NKV   256    // KV*D
#define SCALE_ 0.08838834764831845f  // D^-0.5

typedef __attribute__((ext_vector_type(8))) short  short8;
typedef __attribute__((ext_vector_type(4))) float  floatx4;

__device__ __forceinline__ float b2f(unsigned short u) {
  union { unsigned int i; float f; } v; v.i = ((unsigned int)u) << 16; return v.f;
}
__device__ __forceinline__ unsigned short f2b(float f) {
  union { float f; unsigned int i; } v; v.f = f;
  return (unsigned short)((v.i + 0x7fffu + ((v.i >> 16) & 1u)) >> 16);
}

// ---------------- fp32 -> bf16 elementwise convert (8 elems/thread) ----------------
__global__ __launch_bounds__(256) void k_cvt(const float* __restrict__ in,
                                             unsigned short* __restrict__ out, long n) {
  long i0 = ((long)blockIdx.x * 256 + threadIdx.x) * 8;
  if (i0 >= n) return;
  float4 a = *(const float4*)(in + i0);
  float4 b = *(const float4*)(in + i0 + 4);
  short8 v;
  v[0] = (short)f2b(a.x); v[1] = (short)f2b(a.y);
  v[2] = (short)f2b(a.z); v[3] = (short)f2b(a.w);
  v[4] = (short)f2b(b.x); v[5] = (short)f2b(b.y);
  v[6] = (short)f2b(b.z); v[7] = (short)f2b(b.w);
  *(short8*)(out + i0) = v;
}

// ---------------- prep: gamma/eta (identical) + folded key bias ----------------
__global__ __launch_bounds__(256) void k_prep(const float* __restrict__ prior,
                                              float* __restrict__ ge,
                                              float* __restrict__ kbias) {
  int i = blockIdx.x * 256 + threadIdx.x;
  if (i >= S_) return;
  float p  = prior[i];
  float pc = p * (float)S_;
  float g  = 1.0f + 0.1f * (pc - 1.0f);
  g = fminf(fmaxf(g, 0.9f), 1.1f);
  ge[i] = g;
  float cb = fminf(fmaxf(p, -3.0f), 3.0f);          // clip(BETA_BIAS*prior, -3, 3)
  kbias[i] = cb + logf(1.0f + 0.5f * pc);           // + ln(1 + BETA_POST*pc)
}

// ---------------- transpose + convert: out_bf16[C][R] = in_fp32[R][C] ----------------
__global__ __launch_bounds__(256) void k_transpose(const float* __restrict__ in,
                                                   unsigned short* __restrict__ out,
                                                   int R, int C) {
  __shared__ unsigned short tile[64][68];
  int tx = threadIdx.x & 15, ty = threadIdx.x >> 4;
  long c0 = (long)blockIdx.x * 64, r0 = (long)blockIdx.y * 64;
#pragma unroll
  for (int i = 0; i < 4; i++) {
    int row = ty + 16 * i;
    const float* src = in + (r0 + row) * C + c0 + 4 * tx;
    float4 v = *(const float4*)src;
    tile[row][4 * tx + 0] = f2b(v.x);
    tile[row][4 * tx + 1] = f2b(v.y);
    tile[row][4 * tx + 2] = f2b(v.z);
    tile[row][4 * tx + 3] = f2b(v.w);
  }
  __syncthreads();
#pragma unroll
  for (int i = 0; i < 4; i++) {
    int oc = ty + 16 * i;
    ushort4 v;
    v.x = tile[4 * tx + 0][oc];
    v.y = tile[4 * tx + 1][oc];
    v.z = tile[4 * tx + 2][oc];
    v.w = tile[4 * tx + 3][oc];
    *(ushort4*)(out + (c0 + oc) * R + r0 + 4 * tx) = v;
  }
}

// ---------------- GEMM: C[M][N] = A[M][K] @ Bt[N][K]^T  (bf16 in, fp32 acc) ----------------
// OUT32=0: bf16 output; OUT32=1: fp32 output.
// 128x128 tile, BK=32, 4 waves (2x2), reg-staged LDS (pad 40 elems/row), prefetch.
template <int OUT32>
__global__ __launch_bounds__(256) void k_gemm_bt(const unsigned short* __restrict__ A,
                                                 const unsigned short* __restrict__ Bt,
                                                 void* __restrict__ Cv,
                                                 int M, int N, int K) {
  __shared__ __align__(16) unsigned short As[128 * 40];
  __shared__ __align__(16) unsigned short Bs[128 * 40];
  const int t    = threadIdx.x;
  const int lane = t & 63;
  const int wv   = t >> 6;
  const int wm   = wv >> 1, wn = wv & 1;
  const long m0  = (long)blockIdx.y * 128;
  const long n0  = (long)blockIdx.x * 128;
  const int r15  = lane & 15, g4 = lane >> 4;
  const int row0 = t >> 2, cb = t & 3;

  const unsigned short* Ap0 = A  + (m0 + row0)      * K + cb * 8;
  const unsigned short* Ap1 = A  + (m0 + row0 + 64) * K + cb * 8;
  const unsigned short* Bp0 = Bt + (n0 + row0)      * K + cb * 8;
  const unsigned short* Bp1 = Bt + (n0 + row0 + 64) * K + cb * 8;

  floatx4 acc[4][4];
#pragma unroll
  for (int m = 0; m < 4; m++)
#pragma unroll
    for (int n = 0; n < 4; n++) acc[m][n] = (floatx4){0.f, 0.f, 0.f, 0.f};

  short8 va0 = *(const short8*)(Ap0);
  short8 va1 = *(const short8*)(Ap1);
  short8 vb0 = *(const short8*)(Bp0);
  short8 vb1 = *(const short8*)(Bp1);

  for (int k0 = 0; k0 < K; k0 += 32) {
    *(short8*)(&As[row0 * 40 + cb * 8])        = va0;
    *(short8*)(&As[(row0 + 64) * 40 + cb * 8]) = va1;
    *(short8*)(&Bs[row0 * 40 + cb * 8])        = vb0;
    *(short8*)(&Bs[(row0 + 64) * 40 + cb * 8]) = vb1;
    __syncthreads();
    if (k0 + 32 < K) {  // prefetch next K-step while MFMAs run
      va0 = *(const short8*)(Ap0 + k0 + 32);
      va1 = *(const short8*)(Ap1 + k0 + 32);
      vb0 = *(const short8*)(Bp0 + k0 + 32);
      vb1 = *(const short8*)(Bp1 + k0 + 32);
    }
    short8 af[4], bf[4];
#pragma unroll
    for (int m = 0; m < 4; m++)
      af[m] = *(const short8*)(&As[(wm * 64 + m * 16 + r15) * 40 + g4 * 8]);
#pragma unroll
    for (int n = 0; n < 4; n++)
      bf[n] = *(const short8*)(&Bs[(wn * 64 + n * 16 + r15) * 40 + g4 * 8]);
#pragma unroll
    for (int m = 0; m < 4; m++)
#pragma unroll
      for (int n = 0; n < 4; n++)
        acc[m][n] = __builtin_amdgcn_mfma_f32_16x16x32_bf16(af[m], bf[n], acc[m][n], 0, 0, 0);
    __syncthreads();
  }

#pragma unroll
  for (int m = 0; m < 4; m++) {
    const long rbase = m0 + wm * 64 + m * 16 + g4 * 4;
#pragma unroll
    for (int n = 0; n < 4; n++) {
      const long cidx = n0 + wn * 64 + n * 16 + r15;
#pragma unroll
      for (int i = 0; i < 4; i++) {
        if (OUT32) ((float*)Cv)[(rbase + i) * N + cidx] = acc[m][n][i];
        else ((unsigned short*)Cv)[(rbase + i) * N + cidx] = f2b(acc[m][n][i]);
      }
    }
  }
}

// ---------------- q/k postprocess: RMS norm + RoPE (+gamma for k), one wave per (b,s,head) ----------------
__global__ __launch_bounds__(256) void k_qkpost(const unsigned short* __restrict__ qg,
                                                const unsigned short* __restrict__ kraw,
                                                const float* __restrict__ cosb,
                                                const float* __restrict__ sinb,
                                                const float* __restrict__ ge,
                                                const float* __restrict__ qnw,
                                                const float* __restrict__ knw,
                                                unsigned short* __restrict__ qT,
                                                unsigned short* __restrict__ kT) {
  int wid  = (blockIdx.x * 256 + threadIdx.x) >> 6;
  int lane = threadIdx.x & 63;
  int r    = wid % (H_ + KV_);
  long bs  = wid / (H_ + KV_);
  if (bs >= (long)B_ * S_) return;
  int b = (int)(bs >> 11), s = (int)(bs & 2047);
  int d0 = lane * 2;

  float x0, x1;
  if (r < H_) {
    const unsigned short* src = qg + bs * NQG + r * 256 + d0;
    x0 = b2f(src[0]); x1 = b2f(src[1]);
  } else {
    const unsigned short* src = kraw + bs * NKV + (r - H_) * 128 + d0;
    x0 = b2f(src[0]); x1 = b2f(src[1]);
  }
  float ss = x0 * x0 + x1 * x1;
#pragma unroll
  for (int mask = 1; mask < 64; mask <<= 1) ss += __shfl_xor(ss, mask);
  float rstd = rsqrtf(ss * (1.0f / 128.0f) + 1e-6f);
  float w0, w1;
  if (r < H_) { w0 = qnw[d0]; w1 = qnw[d0 + 1]; }
  else        { w0 = knw[d0]; w1 = knw[d0 + 1]; }
  float xn0 = x0 * rstd * w0, xn1 = x1 * rstd * w1;
  float p0 = __shfl_xor(xn0, 8), p1 = __shfl_xor(xn1, 8);
  float y0 = xn0, y1 = xn1;
  if (lane < 16) {  // d0 < 32 : RoPE region
    float c0 = cosb[bs * ROT_ + d0], c1 = cosb[bs * ROT_ + d0 + 1];
    float s0 = sinb[bs * ROT_ + d0], s1 = sinb[bs * ROT_ + d0 + 1];
    float sgn = (lane < 8) ? -1.0f : 1.0f;  // rot_half: d<16 gets -x[d+16]*sin, 16<=d<32 gets +x[d-16]*sin
    y0 = xn0 * c0 + sgn * p0 * s0;
    y1 = xn1 * c1 + sgn * p1 * s1;
  }
  unsigned int pack;
  if (r < H_) {
    pack = (unsigned int)f2b(y0) | ((unsigned int)f2b(y1) << 16);
    *(unsigned int*)(qT + ((long)(b * H_ + r) * S_ + s) * D_ + d0) = pack;
  } else {
    float g = ge[s];
    pack = (unsigned int)f2b(y0 * g) | ((unsigned int)f2b(y1 * g) << 16);
    *(unsigned int*)(kT + ((long)(b * KV_ + (r - H_)) * S_ + s) * D_ + d0) = pack;
  }
}

// ---------------- v postprocess: scale by eta, write transposed vT[b][kv][d][s] ----------------
__global__ __launch_bounds__(256) void k_vpost(const unsigned short* __restrict__ vraw,
                                               const float* __restrict__ ge,
                                               unsigned short* __restrict__ vT) {
  int bx  = blockIdx.x;
  int scn = bx & 7, d = (bx >> 3) & 127, kvb = (bx >> 10) & 1, b = bx >> 11;
  int s = scn * 256 + threadIdx.x;
  float v = b2f(vraw[((long)(b * S_ + s)) * NKV + kvb * 128 + d]);
  v *= ge[s];
  vT[((long)(b * KV_ + kvb) * D_ + d) * S_ + s] = f2b(v);
}

// ---------------- flash attention: 4 waves, 64 q-rows x 64-key tiles, online softmax ----------------
__global__ __launch_bounds__(256) void k_attn(const unsigned short* __restrict__ qT,
                                              const unsigned short* __restrict__ kT,
                                              const unsigned short* __restrict__ vT,
                                              const float* __restrict__ kbias,
                                              unsigned short* __restrict__ att) {
  __shared__ __align__(16) unsigned short Ks[64 * 136];   // [key][d], pad 136
  __shared__ __align__(16) unsigned short Vs[128 * 72];   // [d][key], pad 72
  __shared__ __align__(16) unsigned short Ps[4][16 * 88]; // per-wave P tile [q][key], pad 88
  const int t = threadIdx.x;
  const int lane = t & 63, wv = t >> 6;
  const int r15 = lane & 15, g4 = lane >> 4;
  const int qt = blockIdx.x & 31;
  const int bh = blockIdx.x >> 5;
  const int b = bh >> 4, hh = bh & 15;
  const int kvh = hh >> 3;  // G = 8
  const int q0 = qt * 64;
  const unsigned short* qbase = qT + ((long)(b * H_ + hh) * S_) * D_;
  const unsigned short* kbase = kT + ((long)(b * KV_ + kvh) * S_) * D_;
  const unsigned short* vbase = vT + ((long)(b * KV_ + kvh) * D_) * S_;

  short8 qf[4];
  {
    const unsigned short* qp = qbase + (long)(q0 + wv * 16 + r15) * D_ + g4 * 8;
#pragma unroll
    for (int kb = 0; kb < 4; kb++) qf[kb] = *(const short8*)(qp + kb * 32);
  }

  floatx4 oacc[8];
#pragma unroll
  for (int nd = 0; nd < 8; nd++) oacc[nd] = (floatx4){0.f, 0.f, 0.f, 0.f};
  float mrow[4] = {-3e38f, -3e38f, -3e38f, -3e38f};
  float lrow[4] = {0.f, 0.f, 0.f, 0.f};

  const int krow = t >> 4, kc16 = t & 15;   // K staging: 16 threads/row, 4 row-iters
  const int srow = t >> 3, sc8 = t & 7;     // V staging: 8 threads/row, 4 row-iters
  const int ntiles = qt + 1;  // causal: key tiles j0 <= q0
  for (int tile = 0; tile < ntiles; tile++) {
    const int j0 = tile * 64;
#pragma unroll
    for (int r = 0; r < 4; r++) {  // stage K tile (64 keys x 128 d)
      int row = krow + 16 * r;
      short8 v = *(const short8*)(kbase + (long)(j0 + row) * D_ + kc16 * 8);
      *(short8*)(&Ks[row * 136 + kc16 * 8]) = v;
    }
#pragma unroll
    for (int r = 0; r < 4; r++) {  // stage V^T tile (128 d x 64 keys)
      int row = srow + 32 * r;
      short8 v = *(const short8*)(vbase + (long)row * S_ + j0 + sc8 * 8);
      *(short8*)(&Vs[row * 72 + sc8 * 8]) = v;
    }
    __syncthreads();

    floatx4 sacc[4];
#pragma unroll
    for (int n = 0; n < 4; n++) sacc[n] = (floatx4){0.f, 0.f, 0.f, 0.f};
#pragma unroll
    for (int kb = 0; kb < 4; kb++)
#pragma unroll
      for (int n = 0; n < 4; n++) {
        short8 bk = *(const short8*)(&Ks[(n * 16 + r15) * 136 + kb * 32 + g4 * 8]);
        sacc[n] = __builtin_amdgcn_mfma_f32_16x16x32_bf16(qf[kb], bk, sacc[n], 0, 0, 0);
      }

    float scf[4][4];
    const bool diag = (j0 == q0);
#pragma unroll
    for (int n = 0; n < 4; n++) {
      const float kb4 = kbias[j0 + n * 16 + r15];
#pragma unroll
      for (int i = 0; i < 4; i++) {
        float v = sacc[n][i] * SCALE_ + kb4;
        if (diag) {
          int ig = q0 + wv * 16 + g4 * 4 + i;
          int jg = j0 + n * 16 + r15;
          if (jg > ig) v = -1e30f;
        }
        scf[n][i] = v;
      }
    }
    float mt[4];
#pragma unroll
    for (int i = 0; i < 4; i++)
      mt[i] = fmaxf(fmaxf(scf[0][i], scf[1][i]), fmaxf(scf[2][i], scf[3][i]));
#pragma unroll
    for (int mask = 1; mask < 16; mask <<= 1)
#pragma unroll
      for (int i = 0; i < 4; i++) mt[i] = fmaxf(mt[i], __shfl_xor(mt[i], mask));
    float alpha[4], rsum[4];
#pragma unroll
    for (int i = 0; i < 4; i++) {
      float mn = fmaxf(mrow[i], mt[i]);
      alpha[i] = __expf(mrow[i] - mn);
      mrow[i] = mn;
      rsum[i] = 0.f;
    }
#pragma unroll
    for (int n = 0; n < 4; n++)
#pragma unroll
      for (int i = 0; i < 4; i++) {
        float p = __expf(scf[n][i] - mrow[i]);
        scf[n][i] = p;
        rsum[i] += p;
      }
#pragma unroll
    for (int mask = 1; mask < 16; mask <<= 1)
#pragma unroll
      for (int i = 0; i < 4; i++) rsum[i] += __shfl_xor(rsum[i], mask);
#pragma unroll
    for (int i = 0; i < 4; i++) lrow[i] = lrow[i] * alpha[i] + rsum[i];
#pragma unroll
    for (int nd = 0; nd < 8; nd++)
#pragma unroll
      for (int i = 0; i < 4; i++) oacc[nd][i] *= alpha[i];

    // P (C-layout) -> LDS bf16 -> A-layout fragments
#pragma unroll
    for (int n = 0; n < 4; n++)
#pragma unroll
      for (int i = 0; i < 4; i++)
        Ps[wv][(g4 * 4 + i) * 88 + n * 16 + r15] = f2b(scf[n][i]);

#pragma unroll
    for (int kb = 0; kb < 2; kb++) {
      short8 pa = *(const short8*)(&Ps[wv][r15 * 88 + kb * 32 + g4 * 8]);
#pragma unroll
      for (int nd = 0; nd < 8; nd++) {
        short8 bv = *(const short8*)(&Vs[(nd * 16 + r15) * 72 + kb * 32 + g4 * 8]);
        oacc[nd] = __builtin_amdgcn_mfma_f32_16x16x32_bf16(pa, bv, oacc[nd], 0, 0, 0);
      }
    }
    __syncthreads();
  }

  unsigned short* abase = att + ((long)(b * H_ + hh) * S_ + q0 + wv * 16) * D_;
#pragma unroll
  for (int i = 0; i < 4; i++) {
    float inv = 1.0f / lrow[i];
#pragma unroll
    for (int nd = 0; nd < 8; nd++)
      abase[(long)(g4 * 4 + i) * D_ + nd * 16 + r15] = f2b(oacc[nd][i] * inv);
  }
}

// ---------------- gate: ag[b][s][h*D+d] = att[b][h][s][d] * sigmoid(gate) ----------------
__global__ __launch_bounds__(256) void k_gate(const unsigned short* __restrict__ att,
                                              const unsigned short* __restrict__ qg,
                                              unsigned short* __restrict__ ag) {
  long idx = (long)blockIdx.x * 256 + threadIdx.x;  // over B*S*H*D
  int d  = (int)(idx & 127);
  int hh = (int)((idx >> 7) & 15);
  long bs = idx >> 11;
  int b = (int)(bs >> 11), s = (int)(bs & 2047);
  float a = b2f(att[((long)(b * H_ + hh) * S_ + s) * D_ + d]);
  float g = b2f(qg[bs * NQG + hh * 256 + 128 + d]);
  float sg = 1.0f / (1.0f + __expf(-g));
  ag[idx] = f2b(a * sg);
}

extern "C" void kernel_launch(void* const* d_in, const int* in_sizes, int n_in,
                              void* d_out, int out_size, void* d_ws, size_t ws_size,
                              hipStream_t stream) {
  const float* h_f   = (const float*)d_in[0];
  const float* cosb  = (const float*)d_in[1];
  const float* sinb  = (const float*)d_in[2];
  // d_in[3] = attention_mask : pure causal, applied analytically
  const float* prior = (const float*)d_in[4];
  const float* Wq    = (const float*)d_in[5];
  const float* Wk    = (const float*)d_in[6];
  const float* Wv    = (const float*)d_in[7];
  const float* Wo    = (const float*)d_in[8];
  const float* qnw   = (const float*)d_in[9];
  const float* knw   = (const float*)d_in[10];

  char* ws = (char*)d_ws;
  size_t off = 0;
  auto alloc = [&](size_t bytes) { char* p = ws + off; off += (bytes + 255) & ~(size_t)255; return p; };
  unsigned short* hb   = (unsigned short*)alloc((size_t)4096 * 2048 * 2);
  unsigned short* WqT  = (unsigned short*)alloc((size_t)4096 * 2048 * 2);
  unsigned short* WkT  = (unsigned short*)alloc((size_t)256 * 2048 * 2);
  unsigned short* WvT  = (unsigned short*)alloc((size_t)256 * 2048 * 2);
  unsigned short* WoT  = (unsigned short*)alloc((size_t)2048 * 2048 * 2);
  unsigned short* qg   = (unsigned short*)alloc((size_t)4096 * 4096 * 2);
  unsigned short* kraw = (unsigned short*)alloc((size_t)4096 * 256 * 2);
  unsigned short* vraw = (unsigned short*)alloc((size_t)4096 * 256 * 2);
  unsigned short* qTb  = (unsigned short*)alloc((size_t)B_ * H_ * S_ * D_ * 2);
  unsigned short* kTb  = (unsigned short*)alloc((size_t)B_ * KV_ * S_ * D_ * 2);
  unsigned short* vTb  = (unsigned short*)alloc((size_t)B_ * KV_ * S_ * D_ * 2);
  float* ge    = (float*)alloc((size_t)S_ * 4);
  float* kbias = (float*)alloc((size_t)S_ * 4);
  // Aliased buffers (sequential stream ordering makes this safe):
  // att reuses WqT (dead after QG GEMM); ag reuses qTb (dead after k_attn).
  unsigned short* att = WqT;
  unsigned short* ag  = qTb;

  dim3 blk(256);
  k_prep<<<dim3(8), blk, 0, stream>>>(prior, ge, kbias);
  k_cvt<<<dim3(4096), blk, 0, stream>>>(h_f, hb, (long)4096 * 2048);
  k_transpose<<<dim3(64, 32), blk, 0, stream>>>(Wq, WqT, 2048, 4096);
  k_transpose<<<dim3(4, 32),  blk, 0, stream>>>(Wk, WkT, 2048, 256);
  k_transpose<<<dim3(4, 32),  blk, 0, stream>>>(Wv, WvT, 2048, 256);
  k_transpose<<<dim3(32, 32), blk, 0, stream>>>(Wo, WoT, 2048, 2048);
  k_gemm_bt<0><<<dim3(32, 32), blk, 0, stream>>>(hb, WqT, qg,   4096, 4096, 2048);
  k_gemm_bt<0><<<dim3(2, 32),  blk, 0, stream>>>(hb, WkT, kraw, 4096, 256,  2048);
  k_gemm_bt<0><<<dim3(2, 32),  blk, 0, stream>>>(hb, WvT, vraw, 4096, 256,  2048);
  k_qkpost<<<dim3(18432), blk, 0, stream>>>(qg, kraw, cosb, sinb, ge, qnw, knw, qTb, kTb);
  k_vpost<<<dim3(4096), blk, 0, stream>>>(vraw, ge, vTb);
  k_attn<<<dim3(1024), blk, 0, stream>>>(qTb, kTb, vTb, kbias, att);
  k_gate<<<dim3(32768), blk, 0, stream>>>(att, qg, ag);
  k_gemm_bt<1><<<dim3(16, 32), blk, 0, stream>>>(ag, WoT, d_out, 4096, 2048, 2048);
}

// Round 5
// 500.221 us; speedup vs baseline: 1.0840x; 1.0840x over previous
//
#include <hip/hip_runtime.h>
#include <hip/hip_bf16.h>
#include <stdint.h>

// Problem constants
#define B_    2
#define S_    2048
#define HID_  2048
#define H_    16
#define KV_   2
#define D_    128
#define ROT_  32
#define NQG   4096   // H*2D
#define NKV   256    // KV*D
#define SCALE_ 0.08838834764831845f  // D^-0.5

typedef __attribute__((ext_vector_type(8))) short  short8;
typedef __attribute__((ext_vector_type(4))) float  floatx4;

__device__ __forceinline__ float b2f(unsigned short u) {
  union { unsigned int i; float f; } v; v.i = ((unsigned int)u) << 16; return v.f;
}
__device__ __forceinline__ unsigned short f2b(float f) {
  union { float f; unsigned int i; } v; v.f = f;
  return (unsigned short)((v.i + 0x7fffu + ((v.i >> 16) & 1u)) >> 16);
}

// ---------------- fp32 -> bf16 elementwise convert (8 elems/thread) ----------------
__global__ __launch_bounds__(256) void k_cvt(const float* __restrict__ in,
                                             unsigned short* __restrict__ out, long n) {
  long i0 = ((long)blockIdx.x * 256 + threadIdx.x) * 8;
  if (i0 >= n) return;
  float4 a = *(const float4*)(in + i0);
  float4 b = *(const float4*)(in + i0 + 4);
  short8 v;
  v[0] = (short)f2b(a.x); v[1] = (short)f2b(a.y);
  v[2] = (short)f2b(a.z); v[3] = (short)f2b(a.w);
  v[4] = (short)f2b(b.x); v[5] = (short)f2b(b.y);
  v[6] = (short)f2b(b.z); v[7] = (short)f2b(b.w);
  *(short8*)(out + i0) = v;
}

// ---------------- prep: gamma/eta (identical) + folded key bias ----------------
__global__ __launch_bounds__(256) void k_prep(const float* __restrict__ prior,
                                              float* __restrict__ ge,
                                              float* __restrict__ kbias) {
  int i = blockIdx.x * 256 + threadIdx.x;
  if (i >= S_) return;
  float p  = prior[i];
  float pc = p * (float)S_;
  float g  = 1.0f + 0.1f * (pc - 1.0f);
  g = fminf(fmaxf(g, 0.9f), 1.1f);
  ge[i] = g;
  float cb = fminf(fmaxf(p, -3.0f), 3.0f);          // clip(BETA_BIAS*prior, -3, 3)
  kbias[i] = cb + logf(1.0f + 0.5f * pc);           // + ln(1 + BETA_POST*pc)
}

// ---------------- transpose + convert: out_bf16[C][R] = in_fp32[R][C] ----------------
__global__ __launch_bounds__(256) void k_transpose(const float* __restrict__ in,
                                                   unsigned short* __restrict__ out,
                                                   int R, int C) {
  __shared__ unsigned short tile[64][68];
  int tx = threadIdx.x & 15, ty = threadIdx.x >> 4;
  long c0 = (long)blockIdx.x * 64, r0 = (long)blockIdx.y * 64;
#pragma unroll
  for (int i = 0; i < 4; i++) {
    int row = ty + 16 * i;
    const float* src = in + (r0 + row) * C + c0 + 4 * tx;
    float4 v = *(const float4*)src;
    tile[row][4 * tx + 0] = f2b(v.x);
    tile[row][4 * tx + 1] = f2b(v.y);
    tile[row][4 * tx + 2] = f2b(v.z);
    tile[row][4 * tx + 3] = f2b(v.w);
  }
  __syncthreads();
#pragma unroll
  for (int i = 0; i < 4; i++) {
    int oc = ty + 16 * i;
    ushort4 v;
    v.x = tile[4 * tx + 0][oc];
    v.y = tile[4 * tx + 1][oc];
    v.z = tile[4 * tx + 2][oc];
    v.w = tile[4 * tx + 3][oc];
    *(ushort4*)(out + (c0 + oc) * R + r0 + 4 * tx) = v;
  }
}

// ---------------- GEMM: C[M][N] = A[M][K] @ Bt[N][K]^T  (bf16 in, fp32 acc) ----------------
// OUT32=0: bf16 output; OUT32=1: fp32 output.
// 128x128 tile, BK=32, 4 waves (2x2), reg-staged LDS (pad 40 elems/row), prefetch.
template <int OUT32>
__global__ __launch_bounds__(256) void k_gemm_bt(const unsigned short* __restrict__ A,
                                                 const unsigned short* __restrict__ Bt,
                                                 void* __restrict__ Cv,
                                                 int M, int N, int K) {
  __shared__ __align__(16) unsigned short As[128 * 40];
  __shared__ __align__(16) unsigned short Bs[128 * 40];
  const int t    = threadIdx.x;
  const int lane = t & 63;
  const int wv   = t >> 6;
  const int wm   = wv >> 1, wn = wv & 1;
  const long m0  = (long)blockIdx.y * 128;
  const long n0  = (long)blockIdx.x * 128;
  const int r15  = lane & 15, g4 = lane >> 4;
  const int row0 = t >> 2, cb = t & 3;

  const unsigned short* Ap0 = A  + (m0 + row0)      * K + cb * 8;
  const unsigned short* Ap1 = A  + (m0 + row0 + 64) * K + cb * 8;
  const unsigned short* Bp0 = Bt + (n0 + row0)      * K + cb * 8;
  const unsigned short* Bp1 = Bt + (n0 + row0 + 64) * K + cb * 8;

  floatx4 acc[4][4];
#pragma unroll
  for (int m = 0; m < 4; m++)
#pragma unroll
    for (int n = 0; n < 4; n++) acc[m][n] = (floatx4){0.f, 0.f, 0.f, 0.f};

  short8 va0 = *(const short8*)(Ap0);
  short8 va1 = *(const short8*)(Ap1);
  short8 vb0 = *(const short8*)(Bp0);
  short8 vb1 = *(const short8*)(Bp1);

  for (int k0 = 0; k0 < K; k0 += 32) {
    *(short8*)(&As[row0 * 40 + cb * 8])        = va0;
    *(short8*)(&As[(row0 + 64) * 40 + cb * 8]) = va1;
    *(short8*)(&Bs[row0 * 40 + cb * 8])        = vb0;
    *(short8*)(&Bs[(row0 + 64) * 40 + cb * 8]) = vb1;
    __syncthreads();
    if (k0 + 32 < K) {  // prefetch next K-step while MFMAs run
      va0 = *(const short8*)(Ap0 + k0 + 32);
      va1 = *(const short8*)(Ap1 + k0 + 32);
      vb0 = *(const short8*)(Bp0 + k0 + 32);
      vb1 = *(const short8*)(Bp1 + k0 + 32);
    }
    short8 af[4], bf[4];
#pragma unroll
    for (int m = 0; m < 4; m++)
      af[m] = *(const short8*)(&As[(wm * 64 + m * 16 + r15) * 40 + g4 * 8]);
#pragma unroll
    for (int n = 0; n < 4; n++)
      bf[n] = *(const short8*)(&Bs[(wn * 64 + n * 16 + r15) * 40 + g4 * 8]);
#pragma unroll
    for (int m = 0; m < 4; m++)
#pragma unroll
      for (int n = 0; n < 4; n++)
        acc[m][n] = __builtin_amdgcn_mfma_f32_16x16x32_bf16(af[m], bf[n], acc[m][n], 0, 0, 0);
    __syncthreads();
  }

#pragma unroll
  for (int m = 0; m < 4; m++) {
    const long rbase = m0 + wm * 64 + m * 16 + g4 * 4;
#pragma unroll
    for (int n = 0; n < 4; n++) {
      const long cidx = n0 + wn * 64 + n * 16 + r15;
#pragma unroll
      for (int i = 0; i < 4; i++) {
        if (OUT32) ((float*)Cv)[(rbase + i) * N + cidx] = acc[m][n][i];
        else ((unsigned short*)Cv)[(rbase + i) * N + cidx] = f2b(acc[m][n][i]);
      }
    }
  }
}

// ---------------- q/k postprocess: RMS norm + RoPE (+gamma for k), one wave per (b,s,head) ----------------
__global__ __launch_bounds__(256) void k_qkpost(const unsigned short* __restrict__ qg,
                                                const unsigned short* __restrict__ kraw,
                                                const float* __restrict__ cosb,
                                                const float* __restrict__ sinb,
                                                const float* __restrict__ ge,
                                                const float* __restrict__ qnw,
                                                const float* __restrict__ knw,
                                                unsigned short* __restrict__ qT,
                                                unsigned short* __restrict__ kT) {
  int wid  = (blockIdx.x * 256 + threadIdx.x) >> 6;
  int lane = threadIdx.x & 63;
  int r    = wid % (H_ + KV_);
  long bs  = wid / (H_ + KV_);
  if (bs >= (long)B_ * S_) return;
  int b = (int)(bs >> 11), s = (int)(bs & 2047);
  int d0 = lane * 2;

  float x0, x1;
  if (r < H_) {
    const unsigned short* src = qg + bs * NQG + r * 256 + d0;
    x0 = b2f(src[0]); x1 = b2f(src[1]);
  } else {
    const unsigned short* src = kraw + bs * NKV + (r - H_) * 128 + d0;
    x0 = b2f(src[0]); x1 = b2f(src[1]);
  }
  float ss = x0 * x0 + x1 * x1;
#pragma unroll
  for (int mask = 1; mask < 64; mask <<= 1) ss += __shfl_xor(ss, mask);
  float rstd = rsqrtf(ss * (1.0f / 128.0f) + 1e-6f);
  float w0, w1;
  if (r < H_) { w0 = qnw[d0]; w1 = qnw[d0 + 1]; }
  else        { w0 = knw[d0]; w1 = knw[d0 + 1]; }
  float xn0 = x0 * rstd * w0, xn1 = x1 * rstd * w1;
  float p0 = __shfl_xor(xn0, 8), p1 = __shfl_xor(xn1, 8);
  float y0 = xn0, y1 = xn1;
  if (lane < 16) {  // d0 < 32 : RoPE region
    float c0 = cosb[bs * ROT_ + d0], c1 = cosb[bs * ROT_ + d0 + 1];
    float s0 = sinb[bs * ROT_ + d0], s1 = sinb[bs * ROT_ + d0 + 1];
    float sgn = (lane < 8) ? -1.0f : 1.0f;  // rot_half: d<16 gets -x[d+16]*sin, 16<=d<32 gets +x[d-16]*sin
    y0 = xn0 * c0 + sgn * p0 * s0;
    y1 = xn1 * c1 + sgn * p1 * s1;
  }
  unsigned int pack;
  if (r < H_) {
    pack = (unsigned int)f2b(y0) | ((unsigned int)f2b(y1) << 16);
    *(unsigned int*)(qT + ((long)(b * H_ + r) * S_ + s) * D_ + d0) = pack;
  } else {
    float g = ge[s];
    pack = (unsigned int)f2b(y0 * g) | ((unsigned int)f2b(y1 * g) << 16);
    *(unsigned int*)(kT + ((long)(b * KV_ + (r - H_)) * S_ + s) * D_ + d0) = pack;
  }
}

// ---------------- v postprocess: scale by eta, write transposed vT[b][kv][d][s] ----------------
__global__ __launch_bounds__(256) void k_vpost(const unsigned short* __restrict__ vraw,
                                               const float* __restrict__ ge,
                                               unsigned short* __restrict__ vT) {
  int bx  = blockIdx.x;
  int scn = bx & 7, d = (bx >> 3) & 127, kvb = (bx >> 10) & 1, b = bx >> 11;
  int s = scn * 256 + threadIdx.x;
  float v = b2f(vraw[((long)(b * S_ + s)) * NKV + kvb * 128 + d]);
  v *= ge[s];
  vT[((long)(b * KV_ + kvb) * D_ + d) * S_ + s] = f2b(v);
}

// ---------------- flash attention, barrier-free: K/V fragments direct from global (L2-resident),
// per-wave P transpose in LDS, fused sigmoid-gate epilogue writing ag[b][s][h*D+d].
// Block decode: XCD-aware (2 XCDs per (b,kvh) group), heavy q-tiles first.
__global__ __launch_bounds__(256) void k_attn(const unsigned short* __restrict__ qT,
                                              const unsigned short* __restrict__ kT,
                                              const unsigned short* __restrict__ vT,
                                              const float* __restrict__ kbias,
                                              const unsigned short* __restrict__ qg,
                                              unsigned short* __restrict__ ag) {
  __shared__ __align__(16) unsigned short Ps[4][16 * 88]; // per-wave P tile [q][key], pad 88
  const int t = threadIdx.x;
  const int lane = t & 63, wv = t >> 6;
  const int r15 = lane & 15, g4 = lane >> 4;
  // XCD swizzle: xcd = p%8 (HW round-robin); group g=(xcd>>1) owns one (b,kvh); heavy qt first.
  const int p = blockIdx.x;
  const int xcd = p & 7;
  const int g = xcd >> 1;                              // 0..3 -> (b,kvh)
  const int member = ((p >> 3) << 1) | (xcd & 1);      // 0..255 within group
  const int bh_local = member & 7;
  const int qt = 31 - (member >> 3);                   // heavy tiles dispatched first
  const int b = g >> 1, kvh = g & 1;
  const int hh = kvh * 8 + bh_local;
  const int q0 = qt * 64;
  const unsigned short* qbase = qT + ((long)(b * H_ + hh) * S_) * D_;
  const unsigned short* kbase = kT + ((long)(b * KV_ + kvh) * S_) * D_;
  const unsigned short* vbase = vT + ((long)(b * KV_ + kvh) * D_) * S_;

  short8 qf[4];
  {
    const unsigned short* qp = qbase + (long)(q0 + wv * 16 + r15) * D_ + g4 * 8;
#pragma unroll
    for (int kb = 0; kb < 4; kb++) qf[kb] = *(const short8*)(qp + kb * 32);
  }

  floatx4 oacc[8];
#pragma unroll
  for (int nd = 0; nd < 8; nd++) oacc[nd] = (floatx4){0.f, 0.f, 0.f, 0.f};
  float mrow[4] = {-3e38f, -3e38f, -3e38f, -3e38f};
  float lrow[4] = {0.f, 0.f, 0.f, 0.f};

  const int ntiles = qt + 1;  // causal: key tiles j0 <= q0
  for (int tile = 0; tile < ntiles; tile++) {
    const int j0 = tile * 64;

    // QK^T: B-fragments direct from global (L2-hot)
    floatx4 sacc[4];
#pragma unroll
    for (int n = 0; n < 4; n++) sacc[n] = (floatx4){0.f, 0.f, 0.f, 0.f};
#pragma unroll
    for (int n = 0; n < 4; n++) {
      const unsigned short* kp = kbase + (long)(j0 + n * 16 + r15) * D_ + g4 * 8;
#pragma unroll
      for (int kb = 0; kb < 4; kb++) {
        short8 bk = *(const short8*)(kp + kb * 32);
        sacc[n] = __builtin_amdgcn_mfma_f32_16x16x32_bf16(qf[kb], bk, sacc[n], 0, 0, 0);
      }
    }

    float scf[4][4];
    const bool diag = (j0 == q0);
#pragma unroll
    for (int n = 0; n < 4; n++) {
      const float kb4 = kbias[j0 + n * 16 + r15];
#pragma unroll
      for (int i = 0; i < 4; i++) {
        float v = sacc[n][i] * SCALE_ + kb4;
        if (diag) {
          int ig = q0 + wv * 16 + g4 * 4 + i;
          int jg = j0 + n * 16 + r15;
          if (jg > ig) v = -1e30f;
        }
        scf[n][i] = v;
      }
    }
    float mt[4];
#pragma unroll
    for (int i = 0; i < 4; i++)
      mt[i] = fmaxf(fmaxf(scf[0][i], scf[1][i]), fmaxf(scf[2][i], scf[3][i]));
#pragma unroll
    for (int mask = 1; mask < 16; mask <<= 1)
#pragma unroll
      for (int i = 0; i < 4; i++) mt[i] = fmaxf(mt[i], __shfl_xor(mt[i], mask));
    float alpha[4], rsum[4];
#pragma unroll
    for (int i = 0; i < 4; i++) {
      float mn = fmaxf(mrow[i], mt[i]);
      alpha[i] = __expf(mrow[i] - mn);
      mrow[i] = mn;
      rsum[i] = 0.f;
    }
#pragma unroll
    for (int n = 0; n < 4; n++)
#pragma unroll
      for (int i = 0; i < 4; i++) {
        float pv = __expf(scf[n][i] - mrow[i]);
        scf[n][i] = pv;
        rsum[i] += pv;
      }
#pragma unroll
    for (int mask = 1; mask < 16; mask <<= 1)
#pragma unroll
      for (int i = 0; i < 4; i++) rsum[i] += __shfl_xor(rsum[i], mask);
#pragma unroll
    for (int i = 0; i < 4; i++) lrow[i] = lrow[i] * alpha[i] + rsum[i];
#pragma unroll
    for (int nd = 0; nd < 8; nd++)
#pragma unroll
      for (int i = 0; i < 4; i++) oacc[nd][i] *= alpha[i];

    // P (C-layout) -> per-wave LDS (no barrier needed) -> A-layout fragments
#pragma unroll
    for (int n = 0; n < 4; n++)
#pragma unroll
      for (int i = 0; i < 4; i++)
        Ps[wv][(g4 * 4 + i) * 88 + n * 16 + r15] = f2b(scf[n][i]);

#pragma unroll
    for (int kb = 0; kb < 2; kb++) {
      short8 pa = *(const short8*)(&Ps[wv][r15 * 88 + kb * 32 + g4 * 8]);
#pragma unroll
      for (int nd = 0; nd < 8; nd++) {
        short8 bv = *(const short8*)(vbase + (long)(nd * 16 + r15) * S_ + j0 + kb * 32 + g4 * 8);
        oacc[nd] = __builtin_amdgcn_mfma_f32_16x16x32_bf16(pa, bv, oacc[nd], 0, 0, 0);
      }
    }
  }

  // Fused gate epilogue: ag[b][s][h*128+d] = (O/l) * sigmoid(gate)
  const long sbase = (long)(b * S_ + q0 + wv * 16 + g4 * 4);
  const unsigned short* gbase = qg + sbase * NQG + hh * 256 + 128;
  unsigned short* abase = ag + sbase * (long)(H_ * D_) + hh * D_;
#pragma unroll
  for (int i = 0; i < 4; i++) {
    float inv = 1.0f / lrow[i];
#pragma unroll
    for (int nd = 0; nd < 8; nd++) {
      int d = nd * 16 + r15;
      float gt = b2f(gbase[(long)i * NQG + d]);
      float sg = 1.0f / (1.0f + __expf(-gt));
      abase[(long)i * (H_ * D_) + d] = f2b(oacc[nd][i] * inv * sg);
    }
  }
}

extern "C" void kernel_launch(void* const* d_in, const int* in_sizes, int n_in,
                              void* d_out, int out_size, void* d_ws, size_t ws_size,
                              hipStream_t stream) {
  const float* h_f   = (const float*)d_in[0];
  const float* cosb  = (const float*)d_in[1];
  const float* sinb  = (const float*)d_in[2];
  // d_in[3] = attention_mask : pure causal, applied analytically
  const float* prior = (const float*)d_in[4];
  const float* Wq    = (const float*)d_in[5];
  const float* Wk    = (const float*)d_in[6];
  const float* Wv    = (const float*)d_in[7];
  const float* Wo    = (const float*)d_in[8];
  const float* qnw   = (const float*)d_in[9];
  const float* knw   = (const float*)d_in[10];

  char* ws = (char*)d_ws;
  size_t off = 0;
  auto alloc = [&](size_t bytes) { char* p = ws + off; off += (bytes + 255) & ~(size_t)255; return p; };
  unsigned short* hb   = (unsigned short*)alloc((size_t)4096 * 2048 * 2);
  unsigned short* WqT  = (unsigned short*)alloc((size_t)4096 * 2048 * 2);
  unsigned short* WkT  = (unsigned short*)alloc((size_t)256 * 2048 * 2);
  unsigned short* WvT  = (unsigned short*)alloc((size_t)256 * 2048 * 2);
  unsigned short* WoT  = (unsigned short*)alloc((size_t)2048 * 2048 * 2);
  unsigned short* qg   = (unsigned short*)alloc((size_t)4096 * 4096 * 2);
  unsigned short* kraw = (unsigned short*)alloc((size_t)4096 * 256 * 2);
  unsigned short* vraw = (unsigned short*)alloc((size_t)4096 * 256 * 2);
  unsigned short* qTb  = (unsigned short*)alloc((size_t)B_ * H_ * S_ * D_ * 2);
  unsigned short* kTb  = (unsigned short*)alloc((size_t)B_ * KV_ * S_ * D_ * 2);
  unsigned short* vTb  = (unsigned short*)alloc((size_t)B_ * KV_ * S_ * D_ * 2);
  float* ge    = (float*)alloc((size_t)S_ * 4);
  float* kbias = (float*)alloc((size_t)S_ * 4);
  // Aliasing (sequential stream order makes these safe):
  // ag reuses hb (hb dead after the three projection GEMMs; k_attn reads qTb/kTb/vTb/qg only).
  unsigned short* ag = hb;

  dim3 blk(256);
  k_prep<<<dim3(8), blk, 0, stream>>>(prior, ge, kbias);
  k_cvt<<<dim3(4096), blk, 0, stream>>>(h_f, hb, (long)4096 * 2048);
  k_transpose<<<dim3(64, 32), blk, 0, stream>>>(Wq, WqT, 2048, 4096);
  k_transpose<<<dim3(4, 32),  blk, 0, stream>>>(Wk, WkT, 2048, 256);
  k_transpose<<<dim3(4, 32),  blk, 0, stream>>>(Wv, WvT, 2048, 256);
  k_transpose<<<dim3(32, 32), blk, 0, stream>>>(Wo, WoT, 2048, 2048);
  k_gemm_bt<0><<<dim3(32, 32), blk, 0, stream>>>(hb, WqT, qg,   4096, 4096, 2048);
  k_gemm_bt<0><<<dim3(2, 32),  blk, 0, stream>>>(hb, WkT, kraw, 4096, 256,  2048);
  k_gemm_bt<0><<<dim3(2, 32),  blk, 0, stream>>>(hb, WvT, vraw, 4096, 256,  2048);
  k_qkpost<<<dim3(18432), blk, 0, stream>>>(qg, kraw, cosb, sinb, ge, qnw, knw, qTb, kTb);
  k_vpost<<<dim3(4096), blk, 0, stream>>>(vraw, ge, vTb);
  k_attn<<<dim3(1024), blk, 0, stream>>>(qTb, kTb, vTb, kbias, qg, ag);
  k_gemm_bt<1><<<dim3(16, 32), blk, 0, stream>>>(ag, WoT, d_out, 4096, 2048, 2048);
}